// Round 4
// baseline (585.769 us; speedup 1.0000x reference)
//
#include <hip/hip_runtime.h>
#include <math.h>

typedef float f4 __attribute__((ext_vector_type(4)));

#define PLANE (4096*4096)

// ---- output offsets (floats), concatenated return order ----
#define OUT_COL 0
#define OUT_ROW 262144
#define OUT_OBJ 524288
#define OUT_CV  524352
#define OUT_VC  34078784
#define OUT_VO  67633216
#define OUT_CO  67641408

// ---- workspace offsets (floats) ----
#define WS_VO_P 0        // [64][64] v->o attention per-block partials
#define WS_CO_P 4096     // [64][64] c->o attention per-block partials
#define WS_OBJ1 8192     // [64]  obj after v->o update
#define WS_RDCV 8256     // [4096] row_hidden . w_cv_row
#define WS_CDCV 12352    // [4096] col_hidden . w_cv_col
#define WS_RDVC 16448    // [4096] row_next . w_vc_row
#define WS_CDVC 20544    // [4096] col_hidden . w_vc_col
#define WS_PART 24640    // [32][4096*64] j-split partials (32 MB)

__device__ __forceinline__ float sigf(float x) {
    return 1.0f / (1.0f + __expf(-x));
}

// async global->LDS, 16B per lane. LDS dest is wave-uniform base + lane*16;
// global src is per-lane. Tracked by vmcnt.
#define AS1 __attribute__((address_space(1)))
#define AS3 __attribute__((address_space(3)))
__device__ __forceinline__ void gl_lds16(const float* g, float* l) {
    __builtin_amdgcn_global_load_lds((const AS1 void*)g, (AS3 void*)l, 16, 0, 0);
}

// ---------------------------------------------------------------------------
// Attention body over 4096 nodes, 64 blocks x 64 nodes (was 16x256: too few
// blocks -> latency-bound). accP[blk][h] partial per block, summed later.
__device__ __forceinline__ void attn_body64(
    int blk, int t, const float* __restrict__ X, const float* __restrict__ supp,
    const float* __restrict__ obj, const float* __restrict__ wat,
    const float* __restrict__ bat, float* __restrict__ accP,
    const float* __restrict__ wextra, float* __restrict__ dextra,
    float* sA, float* sAcc)
{
    const int w = t >> 6, lane = t & 63;
    if (t < 64) {
        const int i = blk * 64 + t;
        float od = 0.f;
        for (int h = 0; h < 64; ++h) od += obj[h] * wat[66 + h];
        float x = bat[0] + od + supp[i*2] * wat[64] + supp[i*2+1] * wat[65];
        const f4* Xr = (const f4*)(X + i*64);
        f4 xd = 0.f, dd = 0.f;
        #pragma unroll
        for (int q = 0; q < 16; ++q) {
            f4 xv = Xr[q];
            xd += xv * ((const f4*)wat)[q];
            if (wextra) dd += xv * ((const f4*)wextra)[q];
        }
        x += xd.x + xd.y + xd.z + xd.w;
        if (dextra) dextra[i] = dd.x + dd.y + dd.z + dd.w;
        sA[t] = sigf(x);
        sAcc[t] = 0.f;
    }
    __syncthreads();
    float partial = 0.f;
    const int jbase = blk * 64 + w * 16;
    for (int j = 0; j < 16; ++j)
        partial += sA[w*16 + j] * X[(jbase + j)*64 + lane];
    atomicAdd(&sAcc[lane], partial);
    __syncthreads();
    if (t < 64) accP[blk*64 + t] = sAcc[t];
}

// ---------------------------------------------------------------------------
// Front kernel: 3072 dot blocks + 16 small-copy blocks + 64 v->o attention blocks.
__global__ __launch_bounds__(256) void k_front(
    const float* __restrict__ col_hidden, const float* __restrict__ row_hidden,
    const float* __restrict__ w_cv_col, const float* __restrict__ w_vc_col,
    const float* __restrict__ w_cv_row,
    float* __restrict__ cdcv, float* __restrict__ cdvc, float* __restrict__ rdcv,
    const float* __restrict__ vo_supp, const float* __restrict__ co_supp,
    float* __restrict__ out_vo, float* __restrict__ out_co,
    const float* __restrict__ obj_hidden, const float* __restrict__ w_attn_vo,
    const float* __restrict__ b_attn_vo, float* __restrict__ voP)
{
    __shared__ float sA[64];
    __shared__ float sAcc[64];
    const int t = threadIdx.x;
    if (blockIdx.x < 3072) {
        const int gw = blockIdx.x * 4 + (t >> 6);
        const int lane = t & 63;
        const int which = gw >> 12;       // 0,1,2
        const int row = gw & 4095;
        const float* x; const float* w; float* dst;
        if (which == 0)      { x = col_hidden; w = w_cv_col; dst = cdcv; }
        else if (which == 1) { x = col_hidden; w = w_vc_col; dst = cdvc; }
        else                 { x = row_hidden; w = w_cv_row; dst = rdcv; }
        float v = x[row * 64 + lane] * w[lane];
        #pragma unroll
        for (int off = 32; off; off >>= 1) v += __shfl_down(v, off, 64);
        if (lane == 0) dst[row] = v;
        return;
    }
    if (blockIdx.x < 3088) {
        const int idx = (blockIdx.x - 3072) * 256 + t;   // 0..4095 f4 units
        if (idx < 2048) ((f4*)out_vo)[idx] = ((const f4*)vo_supp)[idx];
        else            ((f4*)out_co)[idx - 2048] = ((const f4*)co_supp)[idx - 2048];
        return;
    }
    attn_body64(blockIdx.x - 3088, t, col_hidden, vo_supp, obj_hidden,
                w_attn_vo, b_attn_vo, voP, nullptr, nullptr, sA, sAcc);
}

// ---------------------------------------------------------------------------
// Standalone c->o attention (64 blocks), with fused rowdot_vc.
__global__ __launch_bounds__(256) void k_attn(
    const float* __restrict__ X, const float* __restrict__ supp,
    const float* __restrict__ obj, const float* __restrict__ wat,
    const float* __restrict__ bat, float* __restrict__ accP,
    const float* __restrict__ wextra, float* __restrict__ dextra)
{
    __shared__ float sA[64];
    __shared__ float sAcc[64];
    attn_body64(blockIdx.x, threadIdx.x, X, supp, obj, wat, bat, accP,
                wextra, dextra, sA, sAcc);
}

// ---------------------------------------------------------------------------
// Big fused kernel — PRODUCER/CONSUMER WAVE SPECIALIZATION.
//   out(i,h) = sum_j [supp0(i,j)!=0] sig(rdot[i]+cdot[j]+w0*supp0+w1*supp1+b) * B(j,h)
// R3 post-mortem: phased (barrier-separated) structure makes all co-resident
// blocks lockstep through the same phase -> HBM time and LDS-FMA time ADD
// (~9.5us/tile). Fix: one 512-thread block per CU; waves 0-3 consume (FMA
// tile k from LDS), waves 4-7 produce (stage supp k+1 via gl_lds with
// per-wave vmcnt wait, sigmoid+passthrough+in-place scores, B into dead supp1
// region). Producer HBM stalls run UNDER consumer FMA. One barrier/iteration.
// Safety: producer wave stages exactly the row-packs it later sigmoids
// (per-wave vmcnt(0) suffices); B chunks c=pw+4k land in the s1 region the
// same wave read; sched_barrier(0) after asm waitcnts (hoist guard).
// grid = 64 bands * 4 j-groups + 1 obj = 257; 8 tiles of 64x128 per block.
__global__ __launch_bounds__(512, 2) void k_big(
    const float* __restrict__ supp0, const float* __restrict__ supp1,
    const float* __restrict__ Bm,
    const float* __restrict__ rdot, const float* __restrict__ cdot,
    const float* __restrict__ wsup, const float* __restrict__ bias,
    float* __restrict__ part, float* __restrict__ pass0, float* __restrict__ pass1,
    const float* __restrict__ objL, const float* __restrict__ objRp,
    const float* __restrict__ Wobj, float* __restrict__ objDst)
{
    __shared__ __align__(16) float lds[2][2][8192];   // [buf][plane][64*128] = 128 KB
    const int t = threadIdx.x;

    if (blockIdx.x == 256) {
        // obj update: objDst[h] = relu([objL | sum_b objRp[b]] @ Wobj), 64 partials
        if (t < 64) {
            float r = 0.f;
            for (int b = 0; b < 64; ++b) r += objRp[b*64 + t];
            lds[0][0][t] = r;
        }
        __syncthreads();
        if (t < 64) {
            float acc = 0.f;
            for (int k = 0; k < 64; ++k) acc += objL[k] * Wobj[k*64 + t];
            for (int k = 0; k < 64; ++k) acc += lds[0][0][k] * Wobj[(64+k)*64 + t];
            objDst[t] = fmaxf(acc, 0.f);
        }
        return;
    }

    const int bi = blockIdx.x >> 2;       // row band 0..63
    const int jg = blockIdx.x & 3;        // j-group 0..3 (8 tiles of 128 cols each)
    const int i0 = bi * 64;
    const int w = t >> 6, lane = t & 63;
    const float w0 = wsup[0], w1 = wsup[1], bv = bias[0];
    const bool producer = (w >= 4);
    const int pw = w & 3;                 // role-local wave id 0..3

    for (int it = 0; it <= 8; ++it) {
        if (producer && it < 8) {
            float* s0 = &lds[it & 1][0][0];
            float* s1 = &lds[it & 1][1][0];
            const int jt0 = (jg * 8 + it) * 128;
            // -- stage supp: wave pw stages packs p = pw+4k (rows 2p,2p+1) --
            for (int k = 0; k < 8; ++k) {
                const int p = pw + 4 * k;
                const size_t g = (size_t)(i0 + 2*p + (lane >> 5)) * 4096 + jt0 + (lane & 31) * 4;
                gl_lds16(supp0 + g, s0 + p * 256);
                gl_lds16(supp1 + g, s1 + p * 256);
            }
            asm volatile("s_waitcnt vmcnt(0)" ::: "memory");   // own loads only
            __builtin_amdgcn_sched_barrier(0);
            // -- sigmoid + passthrough on own rows (in-place score in s0) --
            const int c4 = (lane & 31) * 4;
            const f4 cd = *(const f4*)(cdot + jt0 + c4);
            for (int q = 0; q < 8; ++q) {
                const int p = q * 4 + pw;
                const int row = 2 * p + (lane >> 5);
                f4 a0 = *(const f4*)(s0 + row * 128 + c4);
                f4 a1 = *(const f4*)(s1 + row * 128 + c4);
                const size_t g = (size_t)(i0 + row) * 4096 + jt0 + c4;
                *(f4*)(pass0 + g) = a0;
                *(f4*)(pass1 + g) = a1;
                const float rd = rdot[i0 + row];
                f4 lg = rd + cd + w0*a0 + w1*a1 + bv;
                f4 s;
                s.x = (a0.x != 0.f) ? sigf(lg.x) : 0.f;
                s.y = (a0.y != 0.f) ? sigf(lg.y) : 0.f;
                s.z = (a0.z != 0.f) ? sigf(lg.z) : 0.f;
                s.w = (a0.w != 0.f) ? sigf(lg.w) : 0.f;
                const int swz = (lane & 31) ^ (((row >> 2) & 3) << 1);
                *(f4*)(s0 + row * 128 + swz * 4) = s;
            }
            asm volatile("s_waitcnt lgkmcnt(0)" ::: "memory"); // reads sampled
            __builtin_amdgcn_sched_barrier(0);
            // -- B tile [128][64] into dead s1; chunk c=pw+4k == own region --
            for (int k = 0; k < 8; ++k) {
                const int c = pw + 4 * k;
                gl_lds16(Bm + (size_t)(jt0 + c * 4) * 64 + lane * 4, s1 + c * 256);
            }
        } else if (!producer && it >= 1) {
            // -- consume tile it-1: rank-128 update, 4 rows x 4 h per thread --
            const float* s0 = &lds[(it - 1) & 1][0][0];
            const float* s1 = &lds[(it - 1) & 1][1][0];
            const int ilb = t >> 4;       // 0..15 -> rows ilb*4..+3
            const int hf4 = t & 15;
            const int sw  = (ilb & 3) << 1;
            f4 acc0 = 0.f, acc1 = 0.f, acc2 = 0.f, acc3 = 0.f;
            #pragma unroll 4
            for (int jf = 0; jf < 32; ++jf) {
                const int jj = jf * 4;
                f4 b0 = *(const f4*)(s1 + (jj + 0) * 64 + hf4 * 4);
                f4 b1 = *(const f4*)(s1 + (jj + 1) * 64 + hf4 * 4);
                f4 b2 = *(const f4*)(s1 + (jj + 2) * 64 + hf4 * 4);
                f4 b3 = *(const f4*)(s1 + (jj + 3) * 64 + hf4 * 4);
                const int sf = (jf ^ sw) * 4;
                { f4 s = *(const f4*)(s0 + (ilb*4 + 0) * 128 + sf); acc0 += s.x*b0 + s.y*b1 + s.z*b2 + s.w*b3; }
                { f4 s = *(const f4*)(s0 + (ilb*4 + 1) * 128 + sf); acc1 += s.x*b0 + s.y*b1 + s.z*b2 + s.w*b3; }
                { f4 s = *(const f4*)(s0 + (ilb*4 + 2) * 128 + sf); acc2 += s.x*b0 + s.y*b1 + s.z*b2 + s.w*b3; }
                { f4 s = *(const f4*)(s0 + (ilb*4 + 3) * 128 + sf); acc3 += s.x*b0 + s.y*b1 + s.z*b2 + s.w*b3; }
            }
            const int js = jg * 8 + (it - 1);
            float* pb = part + (size_t)js * 262144 + (size_t)i0 * 64;
            *(f4*)(pb + (ilb*4 + 0)*64 + hf4*4) = acc0;
            *(f4*)(pb + (ilb*4 + 1)*64 + hf4*4) = acc1;
            *(f4*)(pb + (ilb*4 + 2)*64 + hf4*4) = acc2;
            *(f4*)(pb + (ilb*4 + 3)*64 + hf4*4) = acc3;
        }
        __syncthreads();   // one convergent barrier per iteration
    }
}

// ---------------------------------------------------------------------------
// Two-layer node update, 32-way partial reduction with 1KB-burst part reads:
// wave w loads f4 slices of part[j] (j = w mod 4) -> LDS partials -> cross-wave
// sum. Then mid = relu([objx|base]W1); dst = relu([mid|accin]W2).
__global__ __launch_bounds__(256) void k_mlp2(
    const float* __restrict__ objx, const float* __restrict__ base,
    const float* __restrict__ W1, const float* __restrict__ part,
    const float* __restrict__ W2, float* __restrict__ dst)
{
    __shared__ float mid[4][64];
    __shared__ float accsP[4][256];
    __shared__ float accs[4][64];
    const int t = threadIdx.x, w = t >> 6, h = t & 63, lane = t & 63;
    const int nbase = blockIdx.x * 4;
    // part reduction: each wave-instr reads 1KB contiguous (4 nodes x 64 h)
    f4 v = 0.f;
    for (int j = w; j < 32; j += 4)
        v += *(const f4*)(part + (size_t)j * 262144 + blockIdx.x * 256 + lane * 4);
    *(f4*)&accsP[w][lane * 4] = v;
    // mid layer
    float m = 0.f;
    for (int k = 0; k < 64; ++k) m += objx[k] * W1[k*64 + h];
    for (int k = 0; k < 64; ++k) m += base[(nbase + w)*64 + k] * W1[(64+k)*64 + h];
    mid[w][h] = fmaxf(m, 0.f);
    __syncthreads();
    // reassemble accs: flat position t = n*64+h
    accs[t >> 6][t & 63] = accsP[0][t] + accsP[1][t] + accsP[2][t] + accsP[3][t];
    __syncthreads();
    float o = 0.f;
    for (int k = 0; k < 64; ++k) o += mid[w][k] * W2[k*64 + h];
    for (int k = 0; k < 64; ++k) o += accs[w][k] * W2[(64+k)*64 + h];
    dst[(nbase + w)*64 + h] = fmaxf(o, 0.f);
}

extern "C" void kernel_launch(void* const* d_in, const int* in_sizes, int n_in,
                              void* d_out, int out_size, void* d_ws, size_t ws_size,
                              hipStream_t stream)
{
    const float* col_hidden = (const float*)d_in[0];
    const float* row_hidden = (const float*)d_in[1];
    const float* obj_hidden = (const float*)d_in[2];
    const float* cv_supp    = (const float*)d_in[3];
    const float* vc_supp    = (const float*)d_in[4];
    const float* vo_supp    = (const float*)d_in[5];
    const float* co_supp    = (const float*)d_in[6];
    const float* W_vo       = (const float*)d_in[7];
    const float* W_oc       = (const float*)d_in[8];
    const float* W_vc       = (const float*)d_in[9];
    const float* W_co       = (const float*)d_in[10];
    const float* W_ov       = (const float*)d_in[11];
    const float* W_cv       = (const float*)d_in[12];
    const float* w_attn_vo  = (const float*)d_in[13];
    const float* b_attn_vo  = (const float*)d_in[14];
    const float* w_attn_co  = (const float*)d_in[15];
    const float* b_attn_co  = (const float*)d_in[16];
    const float* w_cv_col   = (const float*)d_in[17];
    const float* w_cv_supp  = (const float*)d_in[18];
    const float* w_cv_row   = (const float*)d_in[19];
    const float* b_cv       = (const float*)d_in[20];
    const float* w_vc_row   = (const float*)d_in[21];
    const float* w_vc_supp  = (const float*)d_in[22];
    const float* w_vc_col   = (const float*)d_in[23];
    const float* b_vc       = (const float*)d_in[24];

    float* out = (float*)d_out;
    float* ws  = (float*)d_ws;

    // 1) dots + small passthrough + v->o attention partials
    k_front<<<3152, 256, 0, stream>>>(col_hidden, row_hidden, w_cv_col, w_vc_col, w_cv_row,
                                      ws + WS_CDCV, ws + WS_CDVC, ws + WS_RDCV,
                                      vo_supp, co_supp, out + OUT_VO, out + OUT_CO,
                                      obj_hidden, w_attn_vo, b_attn_vo, ws + WS_VO_P);
    // 2) v->c big masked matmul (+ fused cv_supp passthrough, + obj v->o update)
    k_big<<<257, 512, 0, stream>>>(cv_supp, cv_supp + PLANE, col_hidden,
                                   ws + WS_RDCV, ws + WS_CDCV, w_cv_supp, b_cv,
                                   ws + WS_PART, out + OUT_CV, out + OUT_CV + PLANE,
                                   obj_hidden, ws + WS_VO_P, W_vo, ws + WS_OBJ1);
    // 3) row_next = relu([relu([obj1|row_hidden]W_oc) | v_out] W_vc)
    k_mlp2<<<1024, 256, 0, stream>>>(ws + WS_OBJ1, row_hidden, W_oc, ws + WS_PART, W_vc,
                                     out + OUT_ROW);
    // 4) c->o attention partials (+ fused rowdot_vc over row_next)
    k_attn<<<64, 256, 0, stream>>>(out + OUT_ROW, co_supp, ws + WS_OBJ1, w_attn_co, b_attn_co,
                                   ws + WS_CO_P, w_vc_row, ws + WS_RDVC);
    // 5) c->v big masked matmul (+ fused vc_supp passthrough, + obj c->o update)
    k_big<<<257, 512, 0, stream>>>(vc_supp, vc_supp + PLANE, out + OUT_ROW,
                                   ws + WS_CDVC, ws + WS_RDVC, w_vc_supp, b_vc,
                                   ws + WS_PART, out + OUT_VC, out + OUT_VC + PLANE,
                                   ws + WS_OBJ1, ws + WS_CO_P, W_co, out + OUT_OBJ);
    // 6) col_next = relu([relu([obj|col_hidden]W_ov) | c_out] W_cv)
    k_mlp2<<<1024, 256, 0, stream>>>(out + OUT_OBJ, col_hidden, W_ov, ws + WS_PART, W_cv,
                                     out + OUT_COL);
}

// Round 7
// 566.876 us; speedup vs baseline: 1.0333x; 1.0333x over previous
//
#include <hip/hip_runtime.h>
#include <math.h>

typedef float f4 __attribute__((ext_vector_type(4)));

#define PLANE (4096*4096)

// ---- output offsets (floats), concatenated return order ----
#define OUT_COL 0
#define OUT_ROW 262144
#define OUT_OBJ 524288
#define OUT_CV  524352
#define OUT_VC  34078784
#define OUT_VO  67633216
#define OUT_CO  67641408

// ---- workspace offsets (floats) ----
#define WS_VO_P 0        // [64][64] v->o attention per-block partials
#define WS_CO_P 4096     // [64][64] c->o attention per-block partials
#define WS_OBJ1 8192     // [64]  obj after v->o update
#define WS_RDCV 8256     // [4096] row_hidden . w_cv_row
#define WS_CDCV 12352    // [4096] col_hidden . w_cv_col
#define WS_RDVC 16448    // [4096] row_next . w_vc_row
#define WS_CDVC 20544    // [4096] col_hidden . w_vc_col
#define WS_PART 24640    // [32][4096*64] j-split partials (32 MB)

__device__ __forceinline__ float sigf(float x) {
    return 1.0f / (1.0f + __expf(-x));
}

#define AS1 __attribute__((address_space(1)))
#define AS3 __attribute__((address_space(3)))
__device__ __forceinline__ void gl_lds16(const float* g, float* l) {
    __builtin_amdgcn_global_load_lds((const AS1 void*)g, (AS3 void*)l, 16, 0, 0);
}

// lgkm-only barrier: makes own ds_writes visible across waves WITHOUT draining
// vmcnt (global stores keep flying). sched_barrier fences compiler motion.
#define LGKM_BARRIER do { \
    asm volatile("s_waitcnt lgkmcnt(0)" ::: "memory"); \
    __builtin_amdgcn_sched_barrier(0); \
    __builtin_amdgcn_s_barrier(); \
    __builtin_amdgcn_sched_barrier(0); } while (0)

// pack score+index: mantissa low 8 bits replaced by tile-local j (0..127).
// relative score error 2^-16 — far below the bf16-grade output threshold.
__device__ __forceinline__ float enc_sj(float s, int j) {
    return __uint_as_float((__float_as_uint(s) & 0xFFFFFF00u) | (unsigned)j);
}

// ---------------------------------------------------------------------------
// Attention body over 4096 nodes, 64 blocks x 64 nodes.
__device__ __forceinline__ void attn_body64(
    int blk, int t, const float* __restrict__ X, const float* __restrict__ supp,
    const float* __restrict__ obj, const float* __restrict__ wat,
    const float* __restrict__ bat, float* __restrict__ accP,
    const float* __restrict__ wextra, float* __restrict__ dextra,
    float* sA, float* sAcc)
{
    const int w = t >> 6, lane = t & 63;
    if (t < 64) {
        const int i = blk * 64 + t;
        float od = 0.f;
        for (int h = 0; h < 64; ++h) od += obj[h] * wat[66 + h];
        float x = bat[0] + od + supp[i*2] * wat[64] + supp[i*2+1] * wat[65];
        const f4* Xr = (const f4*)(X + i*64);
        f4 xd = 0.f, dd = 0.f;
        #pragma unroll
        for (int q = 0; q < 16; ++q) {
            f4 xv = Xr[q];
            xd += xv * ((const f4*)wat)[q];
            if (wextra) dd += xv * ((const f4*)wextra)[q];
        }
        x += xd.x + xd.y + xd.z + xd.w;
        if (dextra) dextra[i] = dd.x + dd.y + dd.z + dd.w;
        sA[t] = sigf(x);
        sAcc[t] = 0.f;
    }
    __syncthreads();
    float partial = 0.f;
    const int jbase = blk * 64 + w * 16;
    for (int j = 0; j < 16; ++j)
        partial += sA[w*16 + j] * X[(jbase + j)*64 + lane];
    atomicAdd(&sAcc[lane], partial);
    __syncthreads();
    if (t < 64) accP[blk*64 + t] = sAcc[t];
}

// ---------------------------------------------------------------------------
// Front kernel: 3072 dot blocks + 16 small-copy blocks + 64 v->o attention blocks.
__global__ __launch_bounds__(256) void k_front(
    const float* __restrict__ col_hidden, const float* __restrict__ row_hidden,
    const float* __restrict__ w_cv_col, const float* __restrict__ w_vc_col,
    const float* __restrict__ w_cv_row,
    float* __restrict__ cdcv, float* __restrict__ cdvc, float* __restrict__ rdcv,
    const float* __restrict__ vo_supp, const float* __restrict__ co_supp,
    float* __restrict__ out_vo, float* __restrict__ out_co,
    const float* __restrict__ obj_hidden, const float* __restrict__ w_attn_vo,
    const float* __restrict__ b_attn_vo, float* __restrict__ voP)
{
    __shared__ float sA[64];
    __shared__ float sAcc[64];
    const int t = threadIdx.x;
    if (blockIdx.x < 3072) {
        const int gw = blockIdx.x * 4 + (t >> 6);
        const int lane = t & 63;
        const int which = gw >> 12;       // 0,1,2
        const int row = gw & 4095;
        const float* x; const float* w; float* dst;
        if (which == 0)      { x = col_hidden; w = w_cv_col; dst = cdcv; }
        else if (which == 1) { x = col_hidden; w = w_vc_col; dst = cdvc; }
        else                 { x = row_hidden; w = w_cv_row; dst = rdcv; }
        float v = x[row * 64 + lane] * w[lane];
        #pragma unroll
        for (int off = 32; off; off >>= 1) v += __shfl_down(v, off, 64);
        if (lane == 0) dst[row] = v;
        return;
    }
    if (blockIdx.x < 3088) {
        const int idx = (blockIdx.x - 3072) * 256 + t;   // 0..4095 f4 units
        if (idx < 2048) ((f4*)out_vo)[idx] = ((const f4*)vo_supp)[idx];
        else            ((f4*)out_co)[idx - 2048] = ((const f4*)co_supp)[idx - 2048];
        return;
    }
    attn_body64(blockIdx.x - 3088, t, col_hidden, vo_supp, obj_hidden,
                w_attn_vo, b_attn_vo, voP, nullptr, nullptr, sA, sAcc);
}

// ---------------------------------------------------------------------------
// Standalone c->o attention (64 blocks), with fused rowdot_vc.
__global__ __launch_bounds__(256) void k_attn(
    const float* __restrict__ X, const float* __restrict__ supp,
    const float* __restrict__ obj, const float* __restrict__ wat,
    const float* __restrict__ bat, float* __restrict__ accP,
    const float* __restrict__ wextra, float* __restrict__ dextra)
{
    __shared__ float sA[64];
    __shared__ float sAcc[64];
    attn_body64(blockIdx.x, threadIdx.x, X, supp, obj, wat, bat, accP,
                wextra, dextra, sA, sAcc);
}

// ---------------------------------------------------------------------------
// Big fused kernel — SPARSE COMPACTION version (R3 phased skeleton, PASSED).
//   out(i,h) = sum_j [supp0(i,j)!=0] sig(rdot[i]+cdot[j]+w0*supp0+w1*supp1+b) * B(j,h)
// Density is 3%: the dense rank-128 FMA (1024 ds_read_b128 + 32K FMA/block)
// multiplied 97% zeros. Phase 2 now packs nonzero (score|j) pairs into the
// DEAD supp1 row region (in-place, read-before-write within the 32-lane row
// group; capacity 126 >> Bin(128,.03); count in slot 127). Phase 3 gathers
// B rows straight from global (1 MB, L2-resident) — no B staging, no dense
// LDS storm. Phase2->3 barrier is lgkm-only: pass stores stay in flight.
// Tile 64x128, LDS = 2x32KB -> 2 blocks/CU. grid = 64*32 + 1 = 2049.
__global__ __launch_bounds__(256, 2) void k_big(
    const float* __restrict__ supp0, const float* __restrict__ supp1,
    const float* __restrict__ Bm,
    const float* __restrict__ rdot, const float* __restrict__ cdot,
    const float* __restrict__ wsup, const float* __restrict__ bias,
    float* __restrict__ part, float* __restrict__ pass0, float* __restrict__ pass1,
    const float* __restrict__ objL, const float* __restrict__ objRp,
    const float* __restrict__ Wobj, float* __restrict__ objDst)
{
    __shared__ __align__(16) float lds0[64*128];   // supp0 tile (32 KB)
    __shared__ __align__(16) float lds1[64*128];   // supp1 tile -> packed lists
    const int t = threadIdx.x;

    if (blockIdx.x == 2048) {
        // obj update: objDst[h] = relu([objL | sum_b objRp[b]] @ Wobj)
        if (t < 64) {
            float r = 0.f;
            for (int b = 0; b < 64; ++b) r += objRp[b*64 + t];
            lds0[t] = r;
        }
        __syncthreads();
        if (t < 64) {
            float acc = 0.f;
            for (int k = 0; k < 64; ++k) acc += objL[k] * Wobj[k*64 + t];
            for (int k = 0; k < 64; ++k) acc += lds0[k] * Wobj[(64+k)*64 + t];
            objDst[t] = fmaxf(acc, 0.f);
        }
        return;
    }

    const int bi = blockIdx.x >> 5;       // row-block 0..63
    const int bj = blockIdx.x & 31;       // j-split 0..31 (fast index)
    const int i0 = bi * 64;
    const int jt0 = bj * 128;
    const int w = t >> 6, lane = t & 63;
    const float w0 = wsup[0], w1 = wsup[1], bv = bias[0];

    // ---- phase 1: stage both supp planes via gl_lds (16 per wave) ----
    // pack p (rows 2p,2p+1): one instruction moves 1 KB (2 x 512 B rows).
    for (int k = 0; k < 8; ++k) {
        const int p = w * 8 + k;          // 0..31
        const size_t g = (size_t)(i0 + 2*p + (lane >> 5)) * 4096 + jt0 + (lane & 31) * 4;
        gl_lds16(supp0 + g, lds0 + p * 256);
        gl_lds16(supp1 + g, lds1 + p * 256);
    }
    __syncthreads();   // drains vmcnt: supp tiles resident

    // ---- phase 2: passthrough + sigmoid + nonzero compaction ----
    // 32-lane group (hi = lane>>5) owns one row per iteration; reads its full
    // row (a0,a1) FIRST, then overwrites the supp1 row region with the packed
    // (score|j) list. Rows are touched by exactly one (wave,q,hi) -> disjoint.
    {
        const int hi  = lane >> 5;
        const int f4c = lane & 31;
        const int sl  = lane & 31;        // segment lane for the scan
        const f4 cd = *(const f4*)(cdot + jt0 + f4c * 4);
        for (int q = 0; q < 8; ++q) {
            const int p = q * 4 + w;
            const int row = 2 * p + hi;   // local row 0..63
            f4 a0 = *(const f4*)(lds0 + row * 128 + f4c * 4);
            f4 a1 = *(const f4*)(lds1 + row * 128 + f4c * 4);
            const size_t g = (size_t)(i0 + row) * 4096 + jt0 + f4c * 4;
            *(f4*)(pass0 + g) = a0;
            *(f4*)(pass1 + g) = a1;
            const float rd = rdot[i0 + row];
            f4 lg = rd + cd + w0 * a0 + w1 * a1 + bv;
            // per-lane nonzero count over its 4 elements
            const int c0 = (a0.x != 0.f), c1 = (a0.y != 0.f);
            const int c2 = (a0.z != 0.f), c3 = (a0.w != 0.f);
            const int m = c0 + c1 + c2 + c3;
            // exclusive prefix sum across the 32-lane segment
            int sum = m;
            #pragma unroll
            for (int d = 1; d < 32; d <<= 1) {
                int x = __shfl_up(sum, d, 32);
                if (sl >= d) sum += x;
            }
            int pos = sum - m;            // exclusive offset
            float* Lrow = lds1 + row * 128;
            if (c0) { if (pos < 126) Lrow[pos] = enc_sj(sigf(lg.x), f4c*4 + 0); ++pos; }
            if (c1) { if (pos < 126) Lrow[pos] = enc_sj(sigf(lg.y), f4c*4 + 1); ++pos; }
            if (c2) { if (pos < 126) Lrow[pos] = enc_sj(sigf(lg.z), f4c*4 + 2); ++pos; }
            if (c3) { if (pos < 126) Lrow[pos] = enc_sj(sigf(lg.w), f4c*4 + 3); ++pos; }
            if (sl == 31) Lrow[127] = __int_as_float(sum < 126 ? sum : 126);
        }
    }
    LGKM_BARRIER;      // lists visible; pass stores still in flight (no vm drain)

    // ---- phase 3: sparse gather-FMA from global B (L2-hot, 1 MB) ----
    // thread (row = t>>2, h-quarter = t&3): ~4 nonzeros avg per 128-j tile.
    {
        const int row = t >> 2;
        const int hq  = t & 3;
        const float* Lrow = lds1 + row * 128;
        const int n = __float_as_int(Lrow[127]);
        f4 acc0 = 0.f, acc1 = 0.f, acc2 = 0.f, acc3 = 0.f;
        for (int k = 0; k < n; ++k) {
            const unsigned u = __float_as_uint(Lrow[k]);
            const int j = (int)(u & 0xFFu);                       // 0..127
            const float s = __uint_as_float(u & 0xFFFFFF00u);
            const f4* Br = (const f4*)(Bm + (size_t)(jt0 + j) * 64 + hq * 16);
            acc0 += s * Br[0];
            acc1 += s * Br[1];
            acc2 += s * Br[2];
            acc3 += s * Br[3];
        }
        float* pb = part + (size_t)bj * 262144 + (size_t)(i0 + row) * 64 + hq * 16;
        *(f4*)(pb + 0)  = acc0;
        *(f4*)(pb + 4)  = acc1;
        *(f4*)(pb + 8)  = acc2;
        *(f4*)(pb + 12) = acc3;
    }
}

// ---------------------------------------------------------------------------
// Two-layer node update, 32-way partial reduction with 1KB-burst part reads.
__global__ __launch_bounds__(256) void k_mlp2(
    const float* __restrict__ objx, const float* __restrict__ base,
    const float* __restrict__ W1, const float* __restrict__ part,
    const float* __restrict__ W2, float* __restrict__ dst)
{
    __shared__ float mid[4][64];
    __shared__ float accsP[4][256];
    __shared__ float accs[4][64];
    const int t = threadIdx.x, w = t >> 6, h = t & 63, lane = t & 63;
    const int nbase = blockIdx.x * 4;
    f4 v = 0.f;
    #pragma unroll
    for (int j = w; j < 32; j += 4)
        v += *(const f4*)(part + (size_t)j * 262144 + blockIdx.x * 256 + lane * 4);
    *(f4*)&accsP[w][lane * 4] = v;
    float m = 0.f;
    for (int k = 0; k < 64; ++k) m += objx[k] * W1[k*64 + h];
    for (int k = 0; k < 64; ++k) m += base[(nbase + w)*64 + k] * W1[(64+k)*64 + h];
    mid[w][h] = fmaxf(m, 0.f);
    __syncthreads();
    accs[t >> 6][t & 63] = accsP[0][t] + accsP[1][t] + accsP[2][t] + accsP[3][t];
    __syncthreads();
    float o = 0.f;
    for (int k = 0; k < 64; ++k) o += mid[w][k] * W2[k*64 + h];
    for (int k = 0; k < 64; ++k) o += accs[w][k] * W2[(64+k)*64 + h];
    dst[(nbase + w)*64 + h] = fmaxf(o, 0.f);
}

extern "C" void kernel_launch(void* const* d_in, const int* in_sizes, int n_in,
                              void* d_out, int out_size, void* d_ws, size_t ws_size,
                              hipStream_t stream)
{
    const float* col_hidden = (const float*)d_in[0];
    const float* row_hidden = (const float*)d_in[1];
    const float* obj_hidden = (const float*)d_in[2];
    const float* cv_supp    = (const float*)d_in[3];
    const float* vc_supp    = (const float*)d_in[4];
    const float* vo_supp    = (const float*)d_in[5];
    const float* co_supp    = (const float*)d_in[6];
    const float* W_vo       = (const float*)d_in[7];
    const float* W_oc       = (const float*)d_in[8];
    const float* W_vc       = (const float*)d_in[9];
    const float* W_co       = (const float*)d_in[10];
    const float* W_ov       = (const float*)d_in[11];
    const float* W_cv       = (const float*)d_in[12];
    const float* w_attn_vo  = (const float*)d_in[13];
    const float* b_attn_vo  = (const float*)d_in[14];
    const float* w_attn_co  = (const float*)d_in[15];
    const float* b_attn_co  = (const float*)d_in[16];
    const float* w_cv_col   = (const float*)d_in[17];
    const float* w_cv_supp  = (const float*)d_in[18];
    const float* w_cv_row   = (const float*)d_in[19];
    const float* b_cv       = (const float*)d_in[20];
    const float* w_vc_row   = (const float*)d_in[21];
    const float* w_vc_supp  = (const float*)d_in[22];
    const float* w_vc_col   = (const float*)d_in[23];
    const float* b_vc       = (const float*)d_in[24];

    float* out = (float*)d_out;
    float* ws  = (float*)d_ws;

    // 1) dots + small passthrough + v->o attention partials
    k_front<<<3152, 256, 0, stream>>>(col_hidden, row_hidden, w_cv_col, w_vc_col, w_cv_row,
                                      ws + WS_CDCV, ws + WS_CDVC, ws + WS_RDCV,
                                      vo_supp, co_supp, out + OUT_VO, out + OUT_CO,
                                      obj_hidden, w_attn_vo, b_attn_vo, ws + WS_VO_P);
    // 2) v->c big masked matmul (+ fused cv_supp passthrough, + obj v->o update)
    k_big<<<2049, 256, 0, stream>>>(cv_supp, cv_supp + PLANE, col_hidden,
                                    ws + WS_RDCV, ws + WS_CDCV, w_cv_supp, b_cv,
                                    ws + WS_PART, out + OUT_CV, out + OUT_CV + PLANE,
                                    obj_hidden, ws + WS_VO_P, W_vo, ws + WS_OBJ1);
    // 3) row_next = relu([relu([obj1|row_hidden]W_oc) | v_out] W_vc)
    k_mlp2<<<1024, 256, 0, stream>>>(ws + WS_OBJ1, row_hidden, W_oc, ws + WS_PART, W_vc,
                                     out + OUT_ROW);
    // 4) c->o attention partials (+ fused rowdot_vc over row_next)
    k_attn<<<64, 256, 0, stream>>>(out + OUT_ROW, co_supp, ws + WS_OBJ1, w_attn_co, b_attn_co,
                                   ws + WS_CO_P, w_vc_row, ws + WS_RDVC);
    // 5) c->v big masked matmul (+ fused vc_supp passthrough, + obj c->o update)
    k_big<<<2049, 256, 0, stream>>>(vc_supp, vc_supp + PLANE, out + OUT_ROW,
                                    ws + WS_CDVC, ws + WS_RDVC, w_vc_supp, b_vc,
                                    ws + WS_PART, out + OUT_VC, out + OUT_VC + PLANE,
                                    ws + WS_OBJ1, ws + WS_CO_P, W_co, out + OUT_OBJ);
    // 6) col_next = relu([relu([obj|col_hidden]W_ov) | c_out] W_cv)
    k_mlp2<<<1024, 256, 0, stream>>>(out + OUT_OBJ, col_hidden, W_ov, ws + WS_PART, W_cv,
                                     out + OUT_COL);
}